// Round 10
// baseline (205.728 us; speedup 1.0000x reference)
//
#include <hip/hip_runtime.h>
#include <hip/hip_fp16.h>
#include <math.h>

// ---- problem constants (match reference) ----
#define NNODES 8704          // B*K = 512*17
#define NEDGE  139264
#define EPLUS  (NEDGE + NNODES)   // 147968 (self-loops appended)
#define NEG_SLOPE 0.2f
#define DEGCAP 64            // fixed CSR slot capacity; deg = Poisson(16)+1, P(>64) ~ 2e-14
#define YSTR   1032          // ylds row stride (halves): 2064B -> 4-spaced banks, 2-way
#define BSTR   40            // B-tile row stride (halves): 80B

typedef _Float16 f16x8 __attribute__((ext_vector_type(8)));
typedef _Float16 f16x4 __attribute__((ext_vector_type(4)));
typedef float    f32x4 __attribute__((ext_vector_type(4)));

__device__ __forceinline__ float lrelu(float v) { return v >= 0.f ? v : NEG_SLOPE * v; }

// ---------------- p vectors + zero cnt + zero layer-2 alpha accumulators ----------------
// p[b][k] = sum_c W[k][h*256+c]*a[h][c];  b = layer*8 + sd*4 + h
__global__ __launch_bounds__(256) void prep_pvec(const float* __restrict__ W1,
                                                 const float* __restrict__ as1,
                                                 const float* __restrict__ ad1,
                                                 const float* __restrict__ W2,
                                                 const float* __restrict__ as2,
                                                 const float* __restrict__ ad2,
                                                 float* __restrict__ pbuf,
                                                 int* __restrict__ cnt,
                                                 float* __restrict__ alphasB /* 2*NNODES*4 */) {
    const int b = blockIdx.x;
    const int t = threadIdx.x;
    for (int i = b * 256 + t; i < NNODES; i += 16 * 256) cnt[i] = 0;
    for (int i = b * 256 + t; i < NNODES * 8; i += 16 * 256) alphasB[i] = 0.f;
    __shared__ float a_sh[256];
    const int layer = b >> 3, sd = (b >> 2) & 1, h = b & 3;
    const float* W  = layer ? W2 : W1;
    const float* av = layer ? (sd ? ad2 : as2) : (sd ? ad1 : as1);
    a_sh[t] = av[h * 256 + t];
    __syncthreads();
    float acc = 0.f;
    const float* Wr = W + (size_t)t * 1024 + h * 256;
#pragma unroll 8
    for (int c = 0; c < 256; ++c) acc += Wr[c] * a_sh[c];
    pbuf[b * 256 + t] = acc;
}

// ---------------- Wcat^T prep: Wcatt[o][h*256+k] = W[k][h*256+o] (fp16), both layers ----------------
__global__ __launch_bounds__(256) void prep_wcat(const float* __restrict__ W1,
                                                 const float* __restrict__ W2,
                                                 _Float16* __restrict__ Wc1,
                                                 _Float16* __restrict__ Wc2) {
    __shared__ float tile[32][33];
    const int k0 = blockIdx.x * 32, o0 = blockIdx.y * 32;
    const int layer = blockIdx.z >> 2, h = blockIdx.z & 3;
    const float* W = layer ? W2 : W1;
    _Float16* Wc   = layer ? Wc2 : Wc1;
    const int t = threadIdx.x;
#pragma unroll
    for (int p = 0; p < 4; ++p) {
        int e = t + p * 256; int kk = e >> 5, oo = e & 31;
        tile[kk][oo] = W[(size_t)(k0 + kk) * 1024 + h * 256 + o0 + oo];
    }
    __syncthreads();
#pragma unroll
    for (int p = 0; p < 4; ++p) {
        int e = t + p * 256; int oo = e >> 5, kk = e & 31;
        Wc[(size_t)(o0 + oo) * 1024 + h * 256 + k0 + kk] = (_Float16)tile[kk][oo];
    }
}

// ---------------- direct-slot CSR scatter ----------------
__global__ void edge_scatter(const int* __restrict__ ei, int* __restrict__ cnt,
                             int* __restrict__ csr) {
    int e = blockIdx.x * 256 + threadIdx.x;
    if (e >= EPLUS) return;
    int src, dst;
    if (e < NEDGE) { src = ei[e]; dst = ei[NEDGE + e]; }
    else           { src = dst = e - NEDGE; }
    int slot = atomicAdd(&cnt[dst], 1);
    if (slot < DEGCAP) csr[dst * DEGCAP + slot] = src;
}

// ---------------- layer-1 alpha dots: asrc/adst[n][h] = x0[n].p[sd*4+h]; also x0 -> fp16 ----------------
__global__ __launch_bounds__(256) void alpha_dots(const float* __restrict__ xf,
                                                  _Float16* __restrict__ xh_out,
                                                  const float* __restrict__ p /* [8][256] */,
                                                  float* __restrict__ asrc,
                                                  float* __restrict__ adst) {
    const int wave = threadIdx.x >> 6, l = threadIdx.x & 63;
    const int n = blockIdx.x * 4 + wave;
    float4 pv[8];
#pragma unroll
    for (int v = 0; v < 8; ++v) pv[v] = *(const float4*)(p + v * 256 + l * 4);
    float4 xv = *(const float4*)(xf + (size_t)n * 256 + l * 4);
    f16x4 hv = {(_Float16)xv.x, (_Float16)xv.y, (_Float16)xv.z, (_Float16)xv.w};
    *(f16x4*)(xh_out + (size_t)n * 256 + l * 4) = hv;
    float d[8];
#pragma unroll
    for (int v = 0; v < 8; ++v)
        d[v] = xv.x * pv[v].x + xv.y * pv[v].y + xv.z * pv[v].z + xv.w * pv[v].w;
#pragma unroll
    for (int off = 1; off <= 32; off <<= 1)
#pragma unroll
        for (int v = 0; v < 8; ++v) d[v] += __shfl_xor(d[v], off);
    if (l == 0) {
        *(float4*)(asrc + n * 4) = make_float4(d[0], d[1], d[2], d[3]);
        *(float4*)(adst + n * 4) = make_float4(d[4], d[5], d[6], d[7]);
    }
}

// ---------------- FUSED softmax + gather + output GEMM ----------------
// Block = 32 dst nodes, 512 threads (8 waves). y never touches HBM:
//  P1+P2: per wave 4 nodes: softmax weights (lanes=slots), gather x rows -> y in LDS (fp16)
//  P3: C[32x256] = 0.25 * y_lds @ Wcatt^T + bias; A-frags direct from y_lds,
//      B double-buffered BK=32 with register prefetch; 1 barrier/step.
//  Epilogue: layer1 -> relu+fp16 x1h + fused layer-2 alpha dots; layer2 -> f32 out.
__global__ __launch_bounds__(512) void agg_gemm(const _Float16* __restrict__ xh,
                                                const int* __restrict__ cnt,
                                                const int* __restrict__ csr,
                                                const float* __restrict__ asrc,
                                                const float* __restrict__ adst,
                                                const _Float16* __restrict__ Wcatt,
                                                const float* __restrict__ bias,
                                                const float* __restrict__ p2,
                                                _Float16* __restrict__ outH,
                                                float* __restrict__ outF,
                                                float* __restrict__ asrc2,
                                                float* __restrict__ adst2) {
    __shared__ __align__(16) _Float16 ylds[32 * YSTR];     // 66.0 KB
    __shared__ __align__(16) _Float16 Bs[2][256 * BSTR];   // 40.0 KB
    __shared__ float p2s[2048];                            // 8 KB
    __shared__ float wbufs[8][DEGCAP * 4];                 // 8 KB
    __shared__ int   sbufs[8][DEGCAP];                     // 2 KB

    const int t   = threadIdx.x;
    const int w   = t >> 6;            // wave 0..7
    const int l   = t & 63;
    const int l15 = l & 15, kb = l >> 4;
    const int bm  = blockIdx.x * 32;

    if (p2) { for (int i = t; i < 2048; i += 512) p2s[i] = p2[i]; }

    // ---- phase 1+2: per wave, 4 nodes ----
    float* wbuf = wbufs[w];
    int*   sbuf = sbufs[w];
#pragma unroll 1
    for (int nl = 0; nl < 4; ++nl) {
        const int row = w * 4 + nl;            // 0..31
        const int n = bm + row;
        int deg = cnt[n]; if (deg > DEGCAP) deg = DEGCAP;
        float4 ad = *(const float4*)(adst + n * 4);
        float w0 = 0.f, w1 = 0.f, w2 = 0.f, w3 = 0.f;
        int src_l = 0;
        if (l < deg) {
            src_l = csr[n * DEGCAP + l];
            float4 as = *(const float4*)(asrc + src_l * 4);
            w0 = __expf(lrelu(as.x + ad.x));
            w1 = __expf(lrelu(as.y + ad.y));
            w2 = __expf(lrelu(as.z + ad.z));
            w3 = __expf(lrelu(as.w + ad.w));
        }
        float d0 = w0, d1 = w1, d2 = w2, d3 = w3;
#pragma unroll
        for (int off = 32; off >= 1; off >>= 1) {
            d0 += __shfl_xor(d0, off);
            d1 += __shfl_xor(d1, off);
            d2 += __shfl_xor(d2, off);
            d3 += __shfl_xor(d3, off);
        }
        if (l < deg) {
            float4 wn = make_float4(w0 / d0, w1 / d1, w2 / d2, w3 / d3);
            *(float4*)(&wbuf[l * 4]) = wn;
            sbuf[l] = src_l;
        }
        __syncthreads();   // uniform: publish wbuf/sbuf (per-wave arrays, block-synced)

        float acc2[4][4] = {};   // [ch_sub][head]
        for (int s = 0; s < deg; ++s) {
            int src = sbuf[s];
            float4 ws = *(const float4*)(&wbuf[s * 4]);   // broadcast
            f16x4 xv = *(const f16x4*)(xh + (size_t)src * 256 + l * 4);
#pragma unroll
            for (int j = 0; j < 4; ++j) {
                float v = (float)xv[j];
                acc2[j][0] += ws.x * v; acc2[j][1] += ws.y * v;
                acc2[j][2] += ws.z * v; acc2[j][3] += ws.w * v;
            }
        }
#pragma unroll
        for (int h = 0; h < 4; ++h) {
            f16x4 pv = {(_Float16)acc2[0][h], (_Float16)acc2[1][h],
                        (_Float16)acc2[2][h], (_Float16)acc2[3][h]};
            *(f16x4*)(&ylds[row * YSTR + h * 256 + l * 4]) = pv;
        }
    }
    __syncthreads();   // y complete

    // ---- phase 3: GEMM ----
    // stage B chunk 0
#pragma unroll
    for (int p = 0; p < 2; ++p) {
        int e = t + p * 512;               // 0..1023
        int col = e >> 2, g = e & 3;
        f16x8 v = *(const f16x8*)(Wcatt + (size_t)col * 1024 + g * 8);
        *(f16x8*)(&Bs[0][col * BSTR + g * 8]) = v;
    }
    __syncthreads();

    f32x4 acc[2][2] = {};
    const int colb = w * 32;
    int a_off[2], b_off[2];
#pragma unroll
    for (int i = 0; i < 2; ++i) a_off[i] = (i * 16 + l15) * YSTR + kb * 8;
#pragma unroll
    for (int j = 0; j < 2; ++j) b_off[j] = (colb + j * 16 + l15) * BSTR + kb * 8;

    int cur = 0;
    for (int s = 0; s < 32; ++s) {
        f16x8 pre[2];
        if (s < 31) {
            int k0n = (s + 1) * 32;
#pragma unroll
            for (int p = 0; p < 2; ++p) {
                int e = t + p * 512;
                int col = e >> 2, g = e & 3;
                pre[p] = *(const f16x8*)(Wcatt + (size_t)col * 1024 + k0n + g * 8);
            }
        }
        f16x8 af[2], bf[2];
#pragma unroll
        for (int i = 0; i < 2; ++i) af[i] = *(const f16x8*)(&ylds[a_off[i] + s * 32]);
#pragma unroll
        for (int j = 0; j < 2; ++j) bf[j] = *(const f16x8*)(&Bs[cur][b_off[j]]);
#pragma unroll
        for (int i = 0; i < 2; ++i)
#pragma unroll
            for (int j = 0; j < 2; ++j)
                acc[i][j] = __builtin_amdgcn_mfma_f32_16x16x32_f16(af[i], bf[j], acc[i][j], 0, 0, 0);
        if (s < 31) {
#pragma unroll
            for (int p = 0; p < 2; ++p) {
                int e = t + p * 512;
                int col = e >> 2, g = e & 3;
                *(f16x8*)(&Bs[cur ^ 1][col * BSTR + g * 8]) = pre[p];
            }
        }
        __syncthreads();
        cur ^= 1;
    }

    // ---- epilogue: C/D layout col=lane&15, row=(lane>>4)*4+q [m89-verified] ----
#pragma unroll
    for (int i = 0; i < 2; ++i)
#pragma unroll
        for (int q = 0; q < 4; ++q) {
            int row = i * 16 + kb * 4 + q;           // 0..31 (node within block)
            int grow = bm + row;
            float rv[2];
#pragma unroll
            for (int j = 0; j < 2; ++j) {
                int col = colb + j * 16 + l15;       // 0..255
                float r = 0.25f * acc[i][j][q] + bias[col];
                rv[j] = r;
                if (outH) outH[(size_t)grow * 256 + col] = (_Float16)fmaxf(r, 0.f);
                else      outF[(size_t)grow * 256 + col] = r;
            }
            if (p2) {
#pragma unroll
                for (int v = 0; v < 8; ++v) {
                    float ps = 0.f;
#pragma unroll
                    for (int j = 0; j < 2; ++j) {
                        int col = colb + j * 16 + l15;
                        ps += fmaxf(rv[j], 0.f) * p2s[v * 256 + col];
                    }
#pragma unroll
                    for (int off = 1; off <= 8; off <<= 1) ps += __shfl_xor(ps, off);
                    if (l15 == 0) {
                        if (v < 4) atomicAdd(&asrc2[grow * 4 + v], ps);
                        else       atomicAdd(&adst2[grow * 4 + (v - 4)], ps);
                    }
                }
            }
        }
}

extern "C" void kernel_launch(void* const* d_in, const int* in_sizes, int n_in,
                              void* d_out, int out_size, void* d_ws, size_t ws_size,
                              hipStream_t stream) {
    const float* x0  = (const float*)d_in[0];
    const int*   ei  = (const int*)d_in[1];
    const float* W1  = (const float*)d_in[2];
    const float* as1 = (const float*)d_in[3];
    const float* ad1 = (const float*)d_in[4];
    const float* b1  = (const float*)d_in[5];
    const float* W2  = (const float*)d_in[6];
    const float* as2 = (const float*)d_in[7];
    const float* ad2 = (const float*)d_in[8];
    const float* b2  = (const float*)d_in[9];
    float* out = (float*)d_out;

    char* w = (char*)d_ws;
    _Float16* x0h = (_Float16*)w; w += (size_t)NNODES * 256 * 2;     // 4.5 MB
    _Float16* x1h = (_Float16*)w; w += (size_t)NNODES * 256 * 2;     // 4.5 MB
    _Float16* Wc1 = (_Float16*)w; w += (size_t)256 * 1024 * 2;       // 512 KB
    _Float16* Wc2 = (_Float16*)w; w += (size_t)256 * 1024 * 2;       // 512 KB
    float* pbuf   = (float*)w;    w += 16 * 256 * 4;                 // 16 KB
    float* asrcA  = (float*)w;    w += NNODES * 4 * 4;
    float* adstA  = (float*)w;    w += NNODES * 4 * 4;
    float* alphasB = (float*)w;   w += NNODES * 8 * 4;               // asrcB+adstB
    float* asrcB  = alphasB;
    float* adstB  = alphasB + NNODES * 4;
    int* cnt      = (int*)w;      w += NNODES * 4;
    int* csr      = (int*)w;      w += (size_t)NNODES * DEGCAP * 4;  // 2.2 MB

    const dim3 eb((EPLUS + 255) / 256);
    const dim3 wcat_grid(8, 8, 8);

    // prep (weights, p-vectors, zero scratch)
    prep_pvec<<<16, 256, 0, stream>>>(W1, as1, ad1, W2, as2, ad2, pbuf, cnt, alphasB);
    prep_wcat<<<wcat_grid, 256, 0, stream>>>(W1, W2, Wc1, Wc2);
    edge_scatter<<<eb, 256, 0, stream>>>(ei, cnt, csr);

    // ---- layer 1 ----
    alpha_dots<<<NNODES / 4, 256, 0, stream>>>(x0, x0h, pbuf, asrcA, adstA);
    agg_gemm<<<NNODES / 32, 512, 0, stream>>>(x0h, cnt, csr, asrcA, adstA, Wc1, b1,
                                              pbuf + 8 * 256, x1h, nullptr, asrcB, adstB);

    // ---- layer 2 ----
    agg_gemm<<<NNODES / 32, 512, 0, stream>>>(x1h, cnt, csr, asrcB, adstB, Wc2, b2,
                                              nullptr, nullptr, out, nullptr, nullptr);
}

// Round 11
// 142.252 us; speedup vs baseline: 1.4462x; 1.4462x over previous
//
#include <hip/hip_runtime.h>
#include <hip/hip_fp16.h>
#include <math.h>

// ---- problem constants (match reference) ----
#define NNODES 8704          // B*K = 512*17
#define NEDGE  139264
#define EPLUS  (NEDGE + NNODES)   // 147968 (self-loops appended)
#define NEG_SLOPE 0.2f
#define DEGCAP 64            // fixed CSR slot capacity; deg = Poisson(16)+1, P(>64) ~ 2e-14
#define LDSK   40            // gemm LDS row stride (32 + 8 fp16) -> 2-way banks

#define NB_PV  16            // prep kernel: pvec blocks
#define NB_WC  512           // prep kernel: wcat blocks (8x8x8 flattened)
#define NB_SC  ((EPLUS + 255) / 256)   // scatter blocks (579)
#define NB_AL  (NNODES / 4)  // alpha blocks (2176)

typedef _Float16 f16x8 __attribute__((ext_vector_type(8)));
typedef _Float16 f16x4 __attribute__((ext_vector_type(4)));
typedef float    f32x4 __attribute__((ext_vector_type(4)));

__device__ __forceinline__ float lrelu(float v) { return v >= 0.f ? v : NEG_SLOPE * v; }

// ---------------- K1: p-vectors (+zero cnt/alphasB) and Wcat^T, one kernel ----------------
__global__ __launch_bounds__(256) void prep_all(const float* __restrict__ W1,
                                                const float* __restrict__ as1,
                                                const float* __restrict__ ad1,
                                                const float* __restrict__ W2,
                                                const float* __restrict__ as2,
                                                const float* __restrict__ ad2,
                                                float* __restrict__ pbuf,
                                                int* __restrict__ cnt,
                                                float* __restrict__ alphasB,
                                                _Float16* __restrict__ Wc1,
                                                _Float16* __restrict__ Wc2) {
    __shared__ float tile[32][33];
    const int b = blockIdx.x;
    const int t = threadIdx.x;
    if (b < NB_PV) {
        // p[b][k] = sum_c W[k][h*256+c]*a[h][c];  b = layer*8 + sd*4 + h
        for (int i = b * 256 + t; i < NNODES; i += NB_PV * 256) cnt[i] = 0;
        for (int i = b * 256 + t; i < NNODES * 8; i += NB_PV * 256) alphasB[i] = 0.f;
        float* a_sh = &tile[0][0];
        const int layer = b >> 3, sd = (b >> 2) & 1, h = b & 3;
        const float* W  = layer ? W2 : W1;
        const float* av = layer ? (sd ? ad2 : as2) : (sd ? ad1 : as1);
        a_sh[t] = av[h * 256 + t];
        __syncthreads();
        float acc = 0.f;
        const float* Wr = W + (size_t)t * 1024 + h * 256;
#pragma unroll 8
        for (int c = 0; c < 256; ++c) acc += Wr[c] * a_sh[c];
        pbuf[b * 256 + t] = acc;
    } else {
        // Wcatt[o][h*256+k] = W[k][h*256+o] (fp16)
        const int idx = b - NB_PV;                 // 0..511
        const int k0 = (idx & 7) * 32, o0 = ((idx >> 3) & 7) * 32;
        const int z = idx >> 6;                    // 0..7
        const int layer = z >> 2, h = z & 3;
        const float* W = layer ? W2 : W1;
        _Float16* Wc   = layer ? Wc2 : Wc1;
#pragma unroll
        for (int p = 0; p < 4; ++p) {
            int e = t + p * 256; int kk = e >> 5, oo = e & 31;
            tile[kk][oo] = W[(size_t)(k0 + kk) * 1024 + h * 256 + o0 + oo];
        }
        __syncthreads();
#pragma unroll
        for (int p = 0; p < 4; ++p) {
            int e = t + p * 256; int oo = e >> 5, kk = e & 31;
            Wc[(size_t)(o0 + oo) * 1024 + h * 256 + k0 + kk] = (_Float16)tile[kk][oo];
        }
    }
}

// ---------------- K2: edge scatter + layer-1 alpha dots, one kernel ----------------
__global__ __launch_bounds__(256) void scatter_alpha(const int* __restrict__ ei,
                                                     int* __restrict__ cnt,
                                                     int* __restrict__ csr,
                                                     const float* __restrict__ xf,
                                                     _Float16* __restrict__ xh_out,
                                                     const float* __restrict__ p /* [8][256] */,
                                                     float* __restrict__ asrc,
                                                     float* __restrict__ adst) {
    const int b = blockIdx.x;
    const int t = threadIdx.x;
    if (b < NB_SC) {
        int e = b * 256 + t;
        if (e >= EPLUS) return;
        int src, dst;
        if (e < NEDGE) { src = ei[e]; dst = ei[NEDGE + e]; }
        else           { src = dst = e - NEDGE; }
        int slot = atomicAdd(&cnt[dst], 1);
        if (slot < DEGCAP) csr[dst * DEGCAP + slot] = src;
    } else {
        const int wave = t >> 6, l = t & 63;
        const int n = (b - NB_SC) * 4 + wave;
        float4 pv[8];
#pragma unroll
        for (int v = 0; v < 8; ++v) pv[v] = *(const float4*)(p + v * 256 + l * 4);
        float4 xv = *(const float4*)(xf + (size_t)n * 256 + l * 4);
        f16x4 hv = {(_Float16)xv.x, (_Float16)xv.y, (_Float16)xv.z, (_Float16)xv.w};
        *(f16x4*)(xh_out + (size_t)n * 256 + l * 4) = hv;
        float d[8];
#pragma unroll
        for (int v = 0; v < 8; ++v)
            d[v] = xv.x * pv[v].x + xv.y * pv[v].y + xv.z * pv[v].z + xv.w * pv[v].w;
#pragma unroll
        for (int off = 1; off <= 32; off <<= 1)
#pragma unroll
            for (int v = 0; v < 8; ++v) d[v] += __shfl_xor(d[v], off);
        if (l == 0) {
            *(float4*)(asrc + n * 4) = make_float4(d[0], d[1], d[2], d[3]);
            *(float4*)(adst + n * 4) = make_float4(d[4], d[5], d[6], d[7]);
        }
    }
}

// ---------------- softmax + x-gather, barrier-free: wave = node ----------------
// Lane = slot for weights; xor-butterfly denominators; shfl-broadcast in gather loop.
// y[n][h*256+c] = sum_src alpha_h * x[src][c]; softmax without max-shift (safe range).
__global__ __launch_bounds__(256) void agg_gather(const _Float16* __restrict__ xh,
                                                  const int* __restrict__ cnt,
                                                  const int* __restrict__ csr,
                                                  const float* __restrict__ asrc,
                                                  const float* __restrict__ adst,
                                                  _Float16* __restrict__ y) {
    const int w = threadIdx.x >> 6, l = threadIdx.x & 63;
    const int n = blockIdx.x * 4 + w;
    int deg = cnt[n]; if (deg > DEGCAP) deg = DEGCAP;

    float4 ad = *(const float4*)(adst + n * 4);
    int src_l = 0;
    float w0 = 0.f, w1 = 0.f, w2 = 0.f, w3 = 0.f;
    if (l < deg) {
        src_l = csr[n * DEGCAP + l];
        float4 as = *(const float4*)(asrc + src_l * 4);
        w0 = __expf(lrelu(as.x + ad.x));
        w1 = __expf(lrelu(as.y + ad.y));
        w2 = __expf(lrelu(as.z + ad.z));
        w3 = __expf(lrelu(as.w + ad.w));
    }
    float d0 = w0, d1 = w1, d2 = w2, d3 = w3;
#pragma unroll
    for (int off = 32; off >= 1; off >>= 1) {
        d0 += __shfl_xor(d0, off);
        d1 += __shfl_xor(d1, off);
        d2 += __shfl_xor(d2, off);
        d3 += __shfl_xor(d3, off);
    }
    w0 /= d0; w1 /= d1; w2 /= d2; w3 /= d3;   // normalized weight of slot l (garbage if l>=deg)

    float acc[4][4] = {};   // [ch_sub][head]
    for (int s = 0; s < deg; ++s) {
        int src = __shfl(src_l, s);
        float u0 = __shfl(w0, s), u1 = __shfl(w1, s);
        float u2 = __shfl(w2, s), u3 = __shfl(w3, s);
        f16x4 xv = *(const f16x4*)(xh + (size_t)src * 256 + l * 4);
#pragma unroll
        for (int j = 0; j < 4; ++j) {
            float v = (float)xv[j];
            acc[j][0] += u0 * v; acc[j][1] += u1 * v;
            acc[j][2] += u2 * v; acc[j][3] += u3 * v;
        }
    }
#pragma unroll
    for (int h = 0; h < 4; ++h) {
        f16x4 pv = {(_Float16)acc[0][h], (_Float16)acc[1][h],
                    (_Float16)acc[2][h], (_Float16)acc[3][h]};
        *(f16x4*)(y + (size_t)n * 1024 + h * 256 + l * 4) = pv;
    }
}

// ---------------- output GEMM: out = 0.25 * Y[8704,1024] @ Wcatt^T + bias ----------------
// (unchanged from R8 best) BM=64, BN=256; 4 waves (2x2), wave=32x128 -> 2x8 frags.
// If p2 != null: fused layer-2 alpha dots from f32 accumulators -> atomicAdd into asrc2/adst2.
__global__ __launch_bounds__(256) void gemm_out(const _Float16* __restrict__ Y,
                                                const _Float16* __restrict__ Wcatt,
                                                const float* __restrict__ bias,
                                                const float* __restrict__ p2,
                                                _Float16* __restrict__ outH,  // relu+fp16 if non-null
                                                float* __restrict__ outF,
                                                float* __restrict__ asrc2,
                                                float* __restrict__ adst2) {
    __shared__ __align__(16) _Float16 As[64 * LDSK];
    __shared__ __align__(16) _Float16 Bs[256 * LDSK];
    __shared__ float p2s[8 * 256];
    const int t    = threadIdx.x;
    const int lane = t & 63;
    const int wave = t >> 6;
    const int wwr = wave >> 1, wwc = wave & 1;
    const int bm = blockIdx.x * 64;
    const int l15 = lane & 15, kb = lane >> 4;

    f32x4 acc[2][8] = {};

    int a_off[2], b_off[8];
#pragma unroll
    for (int i = 0; i < 2; ++i) a_off[i] = (wwr * 32 + i * 16 + l15) * LDSK + kb * 8;
#pragma unroll
    for (int j = 0; j < 8; ++j) b_off[j] = (wwc * 128 + j * 16 + l15) * LDSK + kb * 8;

    for (int k0 = 0; k0 < 1024; k0 += 32) {
        if (k0) __syncthreads();
        // stage A: 64 rows x 32 k (256 chunks of f16x8, 1/thread)
        {
            int row = t >> 2, g = t & 3;
            f16x8 v = *(const f16x8*)(Y + (size_t)(bm + row) * 1024 + k0 + g * 8);
            *(f16x8*)(&As[row * LDSK + g * 8]) = v;
        }
        // stage B: 256 out-cols x 32 k (1024 chunks, 4/thread)
#pragma unroll
        for (int p = 0; p < 4; ++p) {
            int e = t + p * 256;
            int row = e >> 2, g = e & 3;
            f16x8 v = *(const f16x8*)(Wcatt + (size_t)row * 1024 + k0 + g * 8);
            *(f16x8*)(&Bs[row * LDSK + g * 8]) = v;
        }
        __syncthreads();

        f16x8 af[2], bf[8];
#pragma unroll
        for (int i = 0; i < 2; ++i) af[i] = *(const f16x8*)(&As[a_off[i]]);
#pragma unroll
        for (int j = 0; j < 8; ++j) bf[j] = *(const f16x8*)(&Bs[b_off[j]]);
#pragma unroll
        for (int i = 0; i < 2; ++i)
#pragma unroll
            for (int j = 0; j < 8; ++j)
                acc[i][j] = __builtin_amdgcn_mfma_f32_16x16x32_f16(af[i], bf[j], acc[i][j], 0, 0, 0);
    }

    if (p2) {
#pragma unroll
        for (int v = 0; v < 8; ++v) p2s[v * 256 + t] = p2[v * 256 + t];
    }
    __syncthreads();

    // epilogue: C/D layout col=lane&15, row=(lane>>4)*4+q [m89-verified]
#pragma unroll
    for (int i = 0; i < 2; ++i)
#pragma unroll
        for (int q = 0; q < 4; ++q) {
            int row = bm + wwr * 32 + i * 16 + kb * 4 + q;
            float rv[8];
#pragma unroll
            for (int j = 0; j < 8; ++j) {
                int col = wwc * 128 + j * 16 + l15;
                float r = 0.25f * acc[i][j][q] + bias[col];
                rv[j] = r;
                if (outH) outH[(size_t)row * 256 + col] = (_Float16)fmaxf(r, 0.f);
                else      outF[(size_t)row * 256 + col] = r;
            }
            if (p2) {
                // layer-2 alpha dots on relu(x1) rows (f32-exact)
#pragma unroll
                for (int v = 0; v < 8; ++v) {
                    float ps = 0.f;
#pragma unroll
                    for (int j = 0; j < 8; ++j) {
                        int col = wwc * 128 + j * 16 + l15;
                        ps += fmaxf(rv[j], 0.f) * p2s[v * 256 + col];
                    }
#pragma unroll
                    for (int off = 1; off <= 8; off <<= 1) ps += __shfl_xor(ps, off);
                    if (l15 == 0) {
                        if (v < 4) atomicAdd(&asrc2[row * 4 + v], ps);
                        else       atomicAdd(&adst2[row * 4 + (v - 4)], ps);
                    }
                }
            }
        }
}

extern "C" void kernel_launch(void* const* d_in, const int* in_sizes, int n_in,
                              void* d_out, int out_size, void* d_ws, size_t ws_size,
                              hipStream_t stream) {
    const float* x0  = (const float*)d_in[0];
    const int*   ei  = (const int*)d_in[1];
    const float* W1  = (const float*)d_in[2];
    const float* as1 = (const float*)d_in[3];
    const float* ad1 = (const float*)d_in[4];
    const float* b1  = (const float*)d_in[5];
    const float* W2  = (const float*)d_in[6];
    const float* as2 = (const float*)d_in[7];
    const float* ad2 = (const float*)d_in[8];
    const float* b2  = (const float*)d_in[9];
    float* out = (float*)d_out;

    char* w = (char*)d_ws;
    _Float16* y   = (_Float16*)w; w += (size_t)NNODES * 1024 * 2;    // 17.8 MB
    _Float16* x0h = (_Float16*)w; w += (size_t)NNODES * 256 * 2;     // 4.5 MB
    _Float16* x1h = (_Float16*)w; w += (size_t)NNODES * 256 * 2;     // 4.5 MB
    _Float16* Wc1 = (_Float16*)w; w += (size_t)256 * 1024 * 2;       // 512 KB
    _Float16* Wc2 = (_Float16*)w; w += (size_t)256 * 1024 * 2;       // 512 KB
    float* pbuf   = (float*)w;    w += 16 * 256 * 4;                 // 16 KB
    float* asrcA  = (float*)w;    w += NNODES * 4 * 4;
    float* adstA  = (float*)w;    w += NNODES * 4 * 4;
    float* alphasB = (float*)w;   w += NNODES * 8 * 4;               // asrcB+adstB
    float* asrcB  = alphasB;
    float* adstB  = alphasB + NNODES * 4;
    int* cnt      = (int*)w;      w += NNODES * 4;
    int* csr      = (int*)w;      w += (size_t)NNODES * DEGCAP * 4;  // 2.2 MB

    // K1: weights prep + zero scratch (pvec blocks) | Wcat transpose (wcat blocks)
    prep_all<<<NB_PV + NB_WC, 256, 0, stream>>>(W1, as1, ad1, W2, as2, ad2,
                                                pbuf, cnt, alphasB, Wc1, Wc2);
    // K2: CSR scatter | layer-1 alpha dots + x0->fp16
    scatter_alpha<<<NB_SC + NB_AL, 256, 0, stream>>>(ei, cnt, csr, x0, x0h, pbuf, asrcA, adstA);

    // ---- layer 1 ----
    agg_gather<<<NNODES / 4, 256, 0, stream>>>(x0h, cnt, csr, asrcA, adstA, y);
    gemm_out<<<NNODES / 64, 256, 0, stream>>>(y, Wc1, b1, pbuf + 8 * 256, x1h, nullptr, asrcB, adstB);

    // ---- layer 2 ----
    agg_gather<<<NNODES / 4, 256, 0, stream>>>(x1h, cnt, csr, asrcB, adstB, y);
    gemm_out<<<NNODES / 64, 256, 0, stream>>>(y, Wc2, b2, nullptr, nullptr, out, nullptr, nullptr);
}